// Round 3
// baseline (319.346 us; speedup 1.0000x reference)
//
#include <hip/hip_runtime.h>
#include <math.h>

// SSIM loss, (32,3,512,512) fp32, 11x11 sigma=1.5 separable Gaussian, VALID.
// R8 = R7 with the statistics reduced from 5 conv fields to 4.
// R7 post-mortem: removing phase-1 issue waste cut VALU-work 157->110 us-equiv
// but dur_us stayed ~172 (VALUBusy 90->64%, occupancy stuck at 3 blocks/CU,
// LDS-capped): kernel became latency-bound. R8 attacks both sides at once:
// SSIM needs only {mu1, mu2, sig1+sig2, sig12}. With s=x+y, d=x-y:
//   var(s) = sig1+sig2+2sig12,  var(d) = sig1+sig2-2sig12
// so convolving {x, y, s^2, d^2} suffices:
//   sig1+sig2 = (P+M)/2 - mu1^2 - mu2^2,  sig12 = (P-M)/4 - mu1*mu2.
//  - VALU work: phase-1 j-loop 440->352 FMA/task, phase-2 440->352 FMA and
//    90->72 LDS reads/thread  (~-16% total).
//  - LDS 49280->39424 B  ->  4 blocks/CU (16 waves/CU, +33% latency hiding).
//  - Everything else inherited from R7: round-1 full waves w/ SGPR row base,
//    wave-0 tail round, stride-77 scalar b32 LDS (2-way max = free), relu
//    folded into numerator, one rcp, separate finalize kernel (no fences!).

#define WIN   11
#define IMG   512
#define OUT_N 502
#define TO_R  32                 // output rows per block
#define TO_C  64                 // output cols per block
#define TI_C  (TO_C + WIN - 1)   // 74 input cols
#define VB_W  77                 // ODD row stride -> conflict-free scalar reads
#define NF    4                  // conv fields: x, y, (x+y)^2, (x-y)^2
#define C1F   6.5025f
#define C2F   58.5225f
#define GRID_X 8
#define GRID_Y 16
#define GRID_Z 96

struct GaussW { float w[WIN]; };

// Vertical 11-tap over 18 input rows -> 8 output rows x 4 fields, one column.
// CR: clamp rows (only last row-block). CC: clamp column (round-2 tail only).
template<bool CR, bool CC>
__device__ __forceinline__ void vert_task(
    const float* __restrict__ Xp, const float* __restrict__ Yp,
    const GaussW& gw, float (*vb)[TO_R][VB_W],
    int r0, int gc, int i0, int c)
{
    if (CC) gc = min(gc, IMG - 1);
    float a0[8] = {0}, a1[8] = {0}, a2[8] = {0}, a3[8] = {0};
#pragma unroll
    for (int k = 0; k < 18; ++k) {            // 8 outputs need 18 input rows
        int gr = r0 + k;
        if (CR) gr = min(gr, IMG - 1);
        size_t off = (size_t)gr * IMG + gc;   // uniform part scalarizes when
        float x = Xp[off];                    // r0 came from readfirstlane
        float y = Yp[off];
        float s = x + y, d = x - y;
        float ss = s * s, dd = d * d;
        const int jlo = (k > 10) ? (k - 10) : 0;
        const int jhi = (k < 7) ? k : 7;
#pragma unroll
        for (int j = jlo; j <= jhi; ++j) {
            float wv = gw.w[k - j];
            a0[j] += wv * x;
            a1[j] += wv * y;
            a2[j] += wv * ss;
            a3[j] += wv * dd;
        }
    }
#pragma unroll
    for (int j = 0; j < 8; ++j) {             // stride-1 across lanes: free
        int i = i0 + j;
        vb[0][i][c] = a0[j];
        vb[1][i][c] = a1[j];
        vb[2][i][c] = a2[j];
        vb[3][i][c] = a3[j];
    }
}

__global__ __launch_bounds__(256) void ssim_v8_kernel(
    const float* __restrict__ X, const float* __restrict__ Y,
    GaussW gw, double* __restrict__ acc)
{
    // vertically filtered fields: [field][out_row][col], stride 77
    __shared__ float vb[NF][TO_R][VB_W];  // 39424 B -> 4 blocks/CU

    const int plane = blockIdx.z;
    const int ox0 = blockIdx.x * TO_C;    // 64-aligned global columns
    const int oy0 = blockIdx.y * TO_R;
    const float* Xp = X + (size_t)plane * IMG * IMG;
    const float* Yp = Y + (size_t)plane * IMG * IMG;
    const int tid  = threadIdx.x;
    const int wave = tid >> 6;
    const int lane = tid & 63;

    // ---- Phase 1: vertical 11-tap ----
    // Round 1: strip = wave, col = lane. Rows wave-uniform -> SGPR base.
    // gc = ox0 + lane <= 448 + 63 = 511: never needs the col clamp.
    {
        const int r0 = __builtin_amdgcn_readfirstlane(oy0 + wave * 8);
        const int gc = ox0 + lane;
        if (blockIdx.y == GRID_Y - 1)
            vert_task<true,  false>(Xp, Yp, gw, vb, r0, gc, wave * 8, lane);
        else
            vert_task<false, false>(Xp, Yp, gw, vb, r0, gc, wave * 8, lane);
    }
    // Round 2: wave 0 covers the 4 strips x 10 tail cols (c = 64..73).
    // Always fully clamped (40 lanes; clamps are no-ops on interior blocks).
    if (wave == 0 && lane < 40) {
        const int s = lane / 10;              // compiler magic-muls
        const int c = TO_C + (lane - s * 10); // 64..73
        vert_task<true, true>(Xp, Yp, gw, vb, oy0 + s * 8, ox0 + c, s * 8, c);
    }
    __syncthreads();

    // ---- Phase 2: horizontal 11-tap + SSIM, 8 outputs/thread ----
    const int i  = tid >> 3;              // 0..31
    const int c0 = (tid & 7) * 8;         // 0..56
    const int gi = oy0 + i;
    float m[NF][8];
#pragma unroll
    for (int f = 0; f < NF; ++f) {
        float v[18];
#pragma unroll
        for (int k = 0; k < 18; ++k) v[k] = vb[f][i][c0 + k];  // b32, 2-way max
#pragma unroll
        for (int oc = 0; oc < 8; ++oc) {
            float s = 0.f;
#pragma unroll
            for (int k = 0; k < WIN; ++k) s += gw.w[k] * v[oc + k];
            m[f][oc] = s;
        }
    }

    float psum = 0.f;
#pragma unroll
    for (int oc = 0; oc < 8; ++oc) {
        int gj = ox0 + c0 + oc;
        if (gi < OUT_N && gj < OUT_N) {
            float m1 = m[0][oc], m2 = m[1][oc];
            float P  = m[2][oc], M  = m[3][oc];
            float mu1s = m1 * m1, mu2s = m2 * m2, mu12 = m1 * m2;
            float sumvar = 0.5f  * (P + M) - mu1s - mu2s;   // sig1+sig2
            float sig12  = 0.25f * (P - M) - mu12;
            // ssim = [(2mu12+C1)/(mu1s+mu2s+C1)] * relu[(2sig12+C2)/(sumvar+C2)]
            // first factor and both denominators are > 0 -> relu folds into num.
            float num = (2.f * mu12 + C1F) * (2.f * sig12 + C2F);
            float den = (mu1s + mu2s + C1F) * (sumvar + C2F);
            num = fmaxf(num, 0.f);
            psum += num * __builtin_amdgcn_rcpf(den);
        }
    }

    // ---- block reduction ----
#pragma unroll
    for (int off = 32; off > 0; off >>= 1)
        psum += __shfl_down(psum, off, 64);
    __shared__ float wsum[4];
    if ((tid & 63) == 0) wsum[tid >> 6] = psum;
    __syncthreads();
    if (tid == 0) {
        float s = wsum[0] + wsum[1] + wsum[2] + wsum[3];
        atomicAdd(acc, (double)s);            // device-scope by default
    }
}

__global__ void ssim_finalize_kernel(const double* __restrict__ acc,
                                     float* __restrict__ out)
{
    if (threadIdx.x == 0 && blockIdx.x == 0) {
        const double count = (double)GRID_Z * OUT_N * OUT_N;
        out[0] = (float)(1.0 - (*acc) / count);
    }
}

extern "C" void kernel_launch(void* const* d_in, const int* in_sizes, int n_in,
                              void* d_out, int out_size, void* d_ws, size_t ws_size,
                              hipStream_t stream) {
    (void)in_sizes; (void)n_in; (void)out_size; (void)ws_size;
    const float* X = (const float*)d_in[0];
    const float* Y = (const float*)d_in[1];
    float* out = (float*)d_out;
    double* acc = (double*)d_ws;

    hipMemsetAsync(d_ws, 0, sizeof(double), stream);

    GaussW gw;
    {
        double g[WIN], s = 0.0;
        for (int i = 0; i < WIN; ++i) {
            double d = (double)(i - 5);
            g[i] = exp(-(d * d) / (2.0 * 1.5 * 1.5));
            s += g[i];
        }
        for (int i = 0; i < WIN; ++i) gw.w[i] = (float)(g[i] / s);
    }

    dim3 grid(GRID_X, GRID_Y, GRID_Z);        // 8 x 16 x 96
    ssim_v8_kernel<<<grid, 256, 0, stream>>>(X, Y, gw, acc);
    ssim_finalize_kernel<<<1, 64, 0, stream>>>(acc, out);
}

// Round 4
// 258.808 us; speedup vs baseline: 1.2339x; 1.2339x over previous
//
#include <hip/hip_runtime.h>
#include <math.h>

// SSIM loss, (32,3,512,512) fp32, 11x11 sigma=1.5 separable Gaussian, VALID.
// R9 = R8 with the contended atomic removed (single-variable change).
// R5/R7/R8 post-mortem: dur_us pinned at 172-179 us while VALU-work fell
// 157->110->86 us-equiv; L3-resident replay dispatches (hbm ~0) equally slow.
// Invariant suspect: 12288 atomicAdd(double) to ONE address -> serialized
// f64 RMW at one L2 bank. 175us/12288 = 14.2ns = ~34 cyc/atomic: a hard
// floor of N_blocks x t_atomic under the dispatch, independent of compute.
// (Also retro-explains R6: fence+atomic+fence = ~40ns x 12288 = 490us.)
// R9: each block STORES its float partial to ws[blockLinearId] (no RMW);
// finalize kernel reduces the 12288-float array (48 coalesced loads/thread,
// double accumulation). hipMemsetAsync dropped (every slot overwritten).
// Everything else inherited from R8:
//  - 4 conv fields {x, y, (x+y)^2, (x-y)^2}: sig1+sig2 = (P+M)/2 - mu1^2-mu2^2,
//    sig12 = (P-M)/4 - mu1*mu2.  LDS 39424 B -> 4 blocks/CU.
//  - phase-1 round 1: 4 full waves, SGPR row base, clamp-free interior path;
//    round 2: wave 0 does the 4x10 tail cols.
//  - phase-2: stride-77 scalar b32 LDS reads (2-way max = free), 8 outputs/
//    thread, relu folded into SSIM numerator, one rcp.

#define WIN   11
#define IMG   512
#define OUT_N 502
#define TO_R  32                 // output rows per block
#define TO_C  64                 // output cols per block
#define TI_C  (TO_C + WIN - 1)   // 74 input cols
#define VB_W  77                 // ODD row stride -> conflict-free scalar reads
#define NF    4                  // conv fields: x, y, (x+y)^2, (x-y)^2
#define C1F   6.5025f
#define C2F   58.5225f
#define GRID_X 8
#define GRID_Y 16
#define GRID_Z 96
#define NBLOCKS (GRID_X * GRID_Y * GRID_Z)   // 12288

struct GaussW { float w[WIN]; };

// Vertical 11-tap over 18 input rows -> 8 output rows x 4 fields, one column.
// CR: clamp rows (only last row-block). CC: clamp column (round-2 tail only).
template<bool CR, bool CC>
__device__ __forceinline__ void vert_task(
    const float* __restrict__ Xp, const float* __restrict__ Yp,
    const GaussW& gw, float (*vb)[TO_R][VB_W],
    int r0, int gc, int i0, int c)
{
    if (CC) gc = min(gc, IMG - 1);
    float a0[8] = {0}, a1[8] = {0}, a2[8] = {0}, a3[8] = {0};
#pragma unroll
    for (int k = 0; k < 18; ++k) {            // 8 outputs need 18 input rows
        int gr = r0 + k;
        if (CR) gr = min(gr, IMG - 1);
        size_t off = (size_t)gr * IMG + gc;   // uniform part scalarizes when
        float x = Xp[off];                    // r0 came from readfirstlane
        float y = Yp[off];
        float s = x + y, d = x - y;
        float ss = s * s, dd = d * d;
        const int jlo = (k > 10) ? (k - 10) : 0;
        const int jhi = (k < 7) ? k : 7;
#pragma unroll
        for (int j = jlo; j <= jhi; ++j) {
            float wv = gw.w[k - j];
            a0[j] += wv * x;
            a1[j] += wv * y;
            a2[j] += wv * ss;
            a3[j] += wv * dd;
        }
    }
#pragma unroll
    for (int j = 0; j < 8; ++j) {             // stride-1 across lanes: free
        int i = i0 + j;
        vb[0][i][c] = a0[j];
        vb[1][i][c] = a1[j];
        vb[2][i][c] = a2[j];
        vb[3][i][c] = a3[j];
    }
}

__global__ __launch_bounds__(256) void ssim_v9_kernel(
    const float* __restrict__ X, const float* __restrict__ Y,
    GaussW gw, float* __restrict__ partial)
{
    // vertically filtered fields: [field][out_row][col], stride 77
    __shared__ float vb[NF][TO_R][VB_W];  // 39424 B -> 4 blocks/CU

    const int plane = blockIdx.z;
    const int ox0 = blockIdx.x * TO_C;    // 64-aligned global columns
    const int oy0 = blockIdx.y * TO_R;
    const float* Xp = X + (size_t)plane * IMG * IMG;
    const float* Yp = Y + (size_t)plane * IMG * IMG;
    const int tid  = threadIdx.x;
    const int wave = tid >> 6;
    const int lane = tid & 63;

    // ---- Phase 1: vertical 11-tap ----
    // Round 1: strip = wave, col = lane. Rows wave-uniform -> SGPR base.
    // gc = ox0 + lane <= 448 + 63 = 511: never needs the col clamp.
    {
        const int r0 = __builtin_amdgcn_readfirstlane(oy0 + wave * 8);
        const int gc = ox0 + lane;
        if (blockIdx.y == GRID_Y - 1)
            vert_task<true,  false>(Xp, Yp, gw, vb, r0, gc, wave * 8, lane);
        else
            vert_task<false, false>(Xp, Yp, gw, vb, r0, gc, wave * 8, lane);
    }
    // Round 2: wave 0 covers the 4 strips x 10 tail cols (c = 64..73).
    // Always fully clamped (40 lanes; clamps are no-ops on interior blocks).
    if (wave == 0 && lane < 40) {
        const int s = lane / 10;              // compiler magic-muls
        const int c = TO_C + (lane - s * 10); // 64..73
        vert_task<true, true>(Xp, Yp, gw, vb, oy0 + s * 8, ox0 + c, s * 8, c);
    }
    __syncthreads();

    // ---- Phase 2: horizontal 11-tap + SSIM, 8 outputs/thread ----
    const int i  = tid >> 3;              // 0..31
    const int c0 = (tid & 7) * 8;         // 0..56
    const int gi = oy0 + i;
    float m[NF][8];
#pragma unroll
    for (int f = 0; f < NF; ++f) {
        float v[18];
#pragma unroll
        for (int k = 0; k < 18; ++k) v[k] = vb[f][i][c0 + k];  // b32, 2-way max
#pragma unroll
        for (int oc = 0; oc < 8; ++oc) {
            float s = 0.f;
#pragma unroll
            for (int k = 0; k < WIN; ++k) s += gw.w[k] * v[oc + k];
            m[f][oc] = s;
        }
    }

    float psum = 0.f;
#pragma unroll
    for (int oc = 0; oc < 8; ++oc) {
        int gj = ox0 + c0 + oc;
        if (gi < OUT_N && gj < OUT_N) {
            float m1 = m[0][oc], m2 = m[1][oc];
            float P  = m[2][oc], M  = m[3][oc];
            float mu1s = m1 * m1, mu2s = m2 * m2, mu12 = m1 * m2;
            float sumvar = 0.5f  * (P + M) - mu1s - mu2s;   // sig1+sig2
            float sig12  = 0.25f * (P - M) - mu12;
            // ssim = [(2mu12+C1)/(mu1s+mu2s+C1)] * relu[(2sig12+C2)/(sumvar+C2)]
            // first factor and both denominators are > 0 -> relu folds into num.
            float num = (2.f * mu12 + C1F) * (2.f * sig12 + C2F);
            float den = (mu1s + mu2s + C1F) * (sumvar + C2F);
            num = fmaxf(num, 0.f);
            psum += num * __builtin_amdgcn_rcpf(den);
        }
    }

    // ---- block reduction -> one plain store per block (NO atomic) ----
#pragma unroll
    for (int off = 32; off > 0; off >>= 1)
        psum += __shfl_down(psum, off, 64);
    __shared__ float wsum[4];
    if ((tid & 63) == 0) wsum[tid >> 6] = psum;
    __syncthreads();
    if (tid == 0) {
        float s = wsum[0] + wsum[1] + wsum[2] + wsum[3];
        partial[((size_t)blockIdx.z * GRID_Y + blockIdx.y) * GRID_X + blockIdx.x] = s;
    }
}

__global__ __launch_bounds__(256) void ssim_reduce_kernel(
    const float* __restrict__ partial, float* __restrict__ out)
{
    const int tid = threadIdx.x;
    double s = 0.0;
    for (int i = tid; i < NBLOCKS; i += 256)      // 48 coalesced loads/thread
        s += (double)partial[i];
#pragma unroll
    for (int off = 32; off > 0; off >>= 1)
        s += __shfl_down(s, off, 64);
    __shared__ double wsum[4];
    if ((tid & 63) == 0) wsum[tid >> 6] = s;
    __syncthreads();
    if (tid == 0) {
        double a = wsum[0] + wsum[1] + wsum[2] + wsum[3];
        const double count = (double)GRID_Z * OUT_N * OUT_N;
        out[0] = (float)(1.0 - a / count);
    }
}

extern "C" void kernel_launch(void* const* d_in, const int* in_sizes, int n_in,
                              void* d_out, int out_size, void* d_ws, size_t ws_size,
                              hipStream_t stream) {
    (void)in_sizes; (void)n_in; (void)out_size; (void)ws_size;
    const float* X = (const float*)d_in[0];
    const float* Y = (const float*)d_in[1];
    float* out = (float*)d_out;
    float* partial = (float*)d_ws;        // 12288 floats = 48 KiB

    GaussW gw;
    {
        double g[WIN], s = 0.0;
        for (int i = 0; i < WIN; ++i) {
            double d = (double)(i - 5);
            g[i] = exp(-(d * d) / (2.0 * 1.5 * 1.5));
            s += g[i];
        }
        for (int i = 0; i < WIN; ++i) gw.w[i] = (float)(g[i] / s);
    }

    dim3 grid(GRID_X, GRID_Y, GRID_Z);        // 8 x 16 x 96
    ssim_v9_kernel<<<grid, 256, 0, stream>>>(X, Y, gw, partial);
    ssim_reduce_kernel<<<1, 256, 0, stream>>>(partial, out);
}